// Round 20
// baseline (2753.616 us; speedup 1.0000x reference)
//
#include <hip/hip_runtime.h>

#define FPS_N 32768
#define FPS_T 256          // threads per block
#define NBLK 8             // blocks per batch
#define PPB (FPS_N / NBLK) // 4096 points per block
#define PPT (PPB / FPS_T)  // 16 points per thread
#define NCH (PPT / 4)      // 4 four-point chunks per thread
#define NQ 256
#define DD 256
#define B_BATCH 64

// d_ws: u64 slot[64][256][8] = 1 MB, zeroed per launch
#define WS_CLEAR_BYTES (B_BATCH * NQ * NBLK * 8)

// ---------------------------------------------------------------------------
// FUSED kernel: furthest point sampling + fourier embed + 2-layer MLP.
// FPS part: EXACT R12/R18 configuration (empirical optimum ~501us; R13-R17
// proved every sync-chain variant regresses — L3/IF coherence RT floor).
// NEW (R20): the MLP runs inside the FPS kernel's idle waves. Observation:
// waves 1-3 idle ~1.4us/round between barrier1 and barrier2 while wave0
// does store->poll->gather. Every block computes every centroid, so the
// owner block (q == j%8) snapshots query j's coords to LDS (qc) at round j
// and waves 1-3 execute the query's MLP in 3 phases across rounds j+1..j+3:
//   P0: pos[256] = [sin;cos](2pi * norm @ G)      (128 lanes)
//   P1: h[d] = relu(W1[d,:]@pos + b1[d])          (1-2 rows/lane, W from L2)
//   P2: out[d] = relu(W2[d,:]@h + b2[d]) -> store (1-2 rows/lane)
// Phase ~0.5-0.7us < sync window -> hidden. Queries 253-255 finish in a
// barriered epilogue. Eliminates the embed kernel + launch + qxyz roundtrip.
// pack = distbits<<32 | ~idx (monotone f32>=0; ~idx = smallest-index tie-
// break = jnp.argmax). FPS arithmetic matches numpy bitwise (no FMA).
// ---------------------------------------------------------------------------
__global__ __attribute__((amdgpu_flat_work_group_size(FPS_T, FPS_T),
                          amdgpu_waves_per_eu(2, 2)))
void fps_fused_kernel(const float* __restrict__ xyz,
                      const float* __restrict__ pcmin,
                      const float* __restrict__ pcmax,
                      const float* __restrict__ G,
                      const float* __restrict__ W1, const float* __restrict__ b1,
                      const float* __restrict__ W2, const float* __restrict__ b2,
                      float* __restrict__ qout, float* __restrict__ eout,
                      unsigned long long* __restrict__ gslot) {
  const int gid = blockIdx.x;
  const int xcd = gid & 7;          // round-robin dispatch: block i -> XCD i%8
  const int s = gid >> 3;
  const int b = xcd + 8 * (s >> 3); // all 8 eighths of batch b on same XCD
  const int q = s & 7;
  const int t = threadIdx.x;

  const float* __restrict__ base = xyz + (size_t)b * (FPS_N * 3);
  const float4* __restrict__ base4 =
      (const float4*)(base + (size_t)q * PPB * 3) + (size_t)t * (PPT * 3 / 4);
  float* qb = qout + (size_t)b * (NQ * 3);
  float* ob = eout + (size_t)b * (DD * NQ);
  unsigned long long* bslot = gslot + (size_t)b * (NQ * NBLK);

  __shared__ unsigned long long sred[FPS_T / 64];
  __shared__ float4 bc;        // broadcast: cx, cy, cz
  __shared__ float qc[3];      // owner's current query coords (MLP input)
  __shared__ float pos[DD];    // fourier embedding of in-flight query
  __shared__ float hbuf[DD];   // hidden layer of in-flight query

  const float mn0 = pcmin[3 * b + 0], mn1 = pcmin[3 * b + 1], mn2 = pcmin[3 * b + 2];
  const float mx0 = pcmax[3 * b + 0], mx1 = pcmax[3 * b + 1], mx2 = pcmax[3 * b + 2];

  // persistent registers: coords 12 float4 = 48 VGPR, dist 4 float4 = 16 VGPR
  float4 C[PPT * 3 / 4];
#pragma unroll
  for (int i = 0; i < PPT * 3 / 4; ++i) C[i] = base4[i];
#pragma unroll
  for (int i = 0; i < PPT * 3 / 4; ++i) {   // pin: forbid remat
    asm volatile("" : "+v"(C[i].x), "+v"(C[i].y), "+v"(C[i].z), "+v"(C[i].w));
  }
  float4 Dst[NCH];
#pragma unroll
  for (int c = 0; c < NCH; ++c) Dst[c] = make_float4(1e10f, 1e10f, 1e10f, 1e10f);

  if (t == 0) {
    if (q == 0) {
      qb[0] = base[0]; qb[1] = base[1]; qb[2] = base[2];
      qc[0] = base[0]; qc[1] = base[1]; qc[2] = base[2];   // query 0 owner
    }
  }
  float cx = base[0], cy = base[1], cz = base[2];   // inds[0] == 0

#pragma unroll 1
  for (int j = 1; j < NQ; ++j) {
    float best = -1.0f;
    int bik = 0;

#pragma unroll
    for (int c = 0; c < NCH; ++c) {
      const float4 a4 = C[3 * c + 0];
      const float4 b4 = C[3 * c + 1];
      const float4 c4 = C[3 * c + 2];
      // unpack 12 floats -> 4 points (register renaming, no real ops)
      const float px[4] = {a4.x, a4.w, b4.z, c4.y};
      const float py[4] = {a4.y, b4.x, b4.w, c4.z};
      const float pz[4] = {a4.z, b4.y, c4.x, c4.w};
      const float dold[4] = {Dst[c].x, Dst[c].y, Dst[c].z, Dst[c].w};
      float dnew[4];
#pragma unroll
      for (int i = 0; i < 4; ++i) {
        const float dx = __fsub_rn(px[i], cx);
        const float dy = __fsub_rn(py[i], cy);
        const float dz = __fsub_rn(pz[i], cz);
        // numpy order: (dx^2 + dy^2) + dz^2, no fma
        const float d = __fadd_rn(__fadd_rn(__fmul_rn(dx, dx), __fmul_rn(dy, dy)),
                                  __fmul_rn(dz, dz));
        const float nd = fminf(dold[i], d);
        dnew[i] = nd;
        if (nd > best) { best = nd; bik = c * 4 + i; }  // strict >: first occ.
      }
      Dst[c] = make_float4(dnew[0], dnew[1], dnew[2], dnew[3]);
    }
    int bi = q * PPB + t * PPT + bik;   // global point index

    // wave (64-lane) argmax reduce with first-index tie-break
#pragma unroll
    for (int off = 32; off; off >>= 1) {
      const float ov = __shfl_xor(best, off);
      const int oi = __shfl_xor(bi, off);
      if (ov > best || (ov == best && oi < bi)) { best = ov; bi = oi; }
    }
    // pack: monotone in dist (f32>=0), ~idx -> max picks smallest index
    if ((t & 63) == 0) {
      sred[t >> 6] = ((unsigned long long)(unsigned int)__float_as_int(best) << 32) |
                     (unsigned int)~(unsigned int)bi;
    }
    __syncthreads();   // barrier 1

    if (t < 64) {   // wave 0: block combine + cross-block sync (FROZEN R12)
      unsigned long long p = sred[t & 3];
#pragma unroll
      for (int off = 1; off < 4; off <<= 1) {
        const unsigned long long o = __shfl_xor(p, off);
        if (o > p) p = o;
      }
      if (t == 0) {
        __hip_atomic_store(&bslot[j * NBLK + q], p, __ATOMIC_RELAXED,
                           __HIP_MEMORY_SCOPE_AGENT);
      }
      unsigned long long rp = 0;
      if (t < NBLK) {
        const unsigned long long* sl = &bslot[j * NBLK + t];
        do {
          rp = __hip_atomic_load(sl, __ATOMIC_RELAXED, __HIP_MEMORY_SCOPE_AGENT);
        } while (rp == 0ull);
      }
#pragma unroll
      for (int off = 1; off < NBLK; off <<= 1) {
        const unsigned long long o = __shfl_xor(rp, off);
        if (o > rp) rp = o;
      }
      if (t == 0) {
        const int gi = (int)~(unsigned int)(rp & 0xffffffffull);
        const float* cp = base + 3 * (size_t)gi;
        const float ncx = cp[0], ncy = cp[1], ncz = cp[2];
        bc = make_float4(ncx, ncy, ncz, 0.f);
        if (q == 0) { qb[3 * j + 0] = ncx; qb[3 * j + 1] = ncy; qb[3 * j + 2] = ncz; }
        if ((j & 7) == q) { qc[0] = ncx; qc[1] = ncy; qc[2] = ncz; }  // own query j
      }
    } else {
      // waves 1-3: MLP phase for owned query, hidden under wave0's sync
      const int tt = t - 64;                 // 0..191
      const int pm = ((j - 1) - q) & 7;
      const int jq = (j - 1) - pm;
      if (pm < 3 && jq >= 0) {
        if (pm == 0) {
          if (tt < 128) {
            const float nx = (qc[0] - mn0) / (mx0 - mn0);
            const float ny = (qc[1] - mn1) / (mx1 - mn1);
            const float nz = (qc[2] - mn2) / (mx2 - mn2);
            const float sf = nx * G[tt] + ny * G[128 + tt] + nz * G[256 + tt];
            const float pr = 6.28318530717958647692f * sf;
            pos[tt] = sinf(pr);
            pos[tt + 128] = cosf(pr);
          }
        } else if (pm == 1) {
#pragma unroll
          for (int rsel = 0; rsel < 2; ++rsel) {
            const int d = tt + rsel * 192;
            if (rsel == 0 || tt < 64) {
              const float* wr = W1 + (size_t)d * DD;
              float acc = 0.f;
#pragma unroll 8
              for (int c = 0; c < DD; c += 4) {
                const float4 wv = *(const float4*)(wr + c);
                acc = fmaf(wv.x, pos[c + 0], acc);
                acc = fmaf(wv.y, pos[c + 1], acc);
                acc = fmaf(wv.z, pos[c + 2], acc);
                acc = fmaf(wv.w, pos[c + 3], acc);
              }
              hbuf[d] = fmaxf(acc + b1[d], 0.f);
            }
          }
        } else {
#pragma unroll
          for (int rsel = 0; rsel < 2; ++rsel) {
            const int d = tt + rsel * 192;
            if (rsel == 0 || tt < 64) {
              const float* wr = W2 + (size_t)d * DD;
              float acc = 0.f;
#pragma unroll 8
              for (int c = 0; c < DD; c += 4) {
                const float4 wv = *(const float4*)(wr + c);
                acc = fmaf(wv.x, hbuf[c + 0], acc);
                acc = fmaf(wv.y, hbuf[c + 1], acc);
                acc = fmaf(wv.z, hbuf[c + 2], acc);
                acc = fmaf(wv.w, hbuf[c + 3], acc);
              }
              ob[(size_t)d * NQ + jq] = fmaxf(acc + b2[d], 0.f);
            }
          }
        }
      }
    }
    __syncthreads();   // barrier 2
    cx = bc.x; cy = bc.y; cz = bc.z;
  }

  // epilogue: leftover phases for queries 253-255 (virtual rounds 256-258)
#pragma unroll 1
  for (int j = NQ; j < NQ + 3; ++j) {
    if (t >= 64) {
      const int tt = t - 64;
      const int pm = ((j - 1) - q) & 7;
      const int jq = (j - 1) - pm;
      if (pm < 3 && jq >= 0 && jq < NQ) {
        if (pm == 0) {
          if (tt < 128) {
            const float nx = (qc[0] - mn0) / (mx0 - mn0);
            const float ny = (qc[1] - mn1) / (mx1 - mn1);
            const float nz = (qc[2] - mn2) / (mx2 - mn2);
            const float sf = nx * G[tt] + ny * G[128 + tt] + nz * G[256 + tt];
            const float pr = 6.28318530717958647692f * sf;
            pos[tt] = sinf(pr);
            pos[tt + 128] = cosf(pr);
          }
        } else if (pm == 1) {
#pragma unroll
          for (int rsel = 0; rsel < 2; ++rsel) {
            const int d = tt + rsel * 192;
            if (rsel == 0 || tt < 64) {
              const float* wr = W1 + (size_t)d * DD;
              float acc = 0.f;
#pragma unroll 8
              for (int c = 0; c < DD; c += 4) {
                const float4 wv = *(const float4*)(wr + c);
                acc = fmaf(wv.x, pos[c + 0], acc);
                acc = fmaf(wv.y, pos[c + 1], acc);
                acc = fmaf(wv.z, pos[c + 2], acc);
                acc = fmaf(wv.w, pos[c + 3], acc);
              }
              hbuf[d] = fmaxf(acc + b1[d], 0.f);
            }
          }
        } else {
#pragma unroll
          for (int rsel = 0; rsel < 2; ++rsel) {
            const int d = tt + rsel * 192;
            if (rsel == 0 || tt < 64) {
              const float* wr = W2 + (size_t)d * DD;
              float acc = 0.f;
#pragma unroll 8
              for (int c = 0; c < DD; c += 4) {
                const float4 wv = *(const float4*)(wr + c);
                acc = fmaf(wv.x, hbuf[c + 0], acc);
                acc = fmaf(wv.y, hbuf[c + 1], acc);
                acc = fmaf(wv.z, hbuf[c + 2], acc);
                acc = fmaf(wv.w, hbuf[c + 3], acc);
              }
              ob[(size_t)d * NQ + jq] = fmaxf(acc + b2[d], 0.f);
            }
          }
        }
      }
    }
    __syncthreads();
  }
}

extern "C" void kernel_launch(void* const* d_in, const int* in_sizes, int n_in,
                              void* d_out, int out_size, void* d_ws, size_t ws_size,
                              hipStream_t stream) {
  (void)in_sizes; (void)n_in; (void)ws_size; (void)out_size;
  const float* xyz   = (const float*)d_in[0];
  const float* pcmin = (const float*)d_in[1];
  const float* pcmax = (const float*)d_in[2];
  const float* G     = (const float*)d_in[3];
  const float* W1    = (const float*)d_in[4];
  const float* b1    = (const float*)d_in[5];
  const float* W2    = (const float*)d_in[6];
  const float* b2    = (const float*)d_in[7];

  float* qxyz  = (float*)d_out;                       // [64][256][3]
  float* embed = qxyz + (size_t)B_BATCH * NQ * 3;     // [64][256][256]

  unsigned long long* gslot = (unsigned long long*)d_ws;

  // clear sync slots every launch (deterministic across graph replays)
  hipMemsetAsync(d_ws, 0, WS_CLEAR_BYTES, stream);

  hipLaunchKernelGGL(fps_fused_kernel, dim3(B_BATCH * NBLK), dim3(FPS_T), 0,
                     stream, xyz, pcmin, pcmax, G, W1, b1, W2, b2,
                     qxyz, embed, gslot);
}

// Round 21
// 622.426 us; speedup vs baseline: 4.4240x; 4.4240x over previous
//
#include <hip/hip_runtime.h>

#define FPS_N 32768
#define FPS_T 256          // threads per block
#define NBLK 8             // fps blocks per batch
#define PPB (FPS_N / NBLK) // 4096 points per block
#define PPT (PPB / FPS_T)  // 16 points per thread
#define NCH (PPT / 4)      // 4 four-point chunks per thread
#define NQ 256
#define DD 256
#define B_BATCH 64
#define FPS_BLOCKS (B_BATCH * NBLK)   // 512
#define EMB_BLOCKS (B_BATCH * 4)      // 256 (4 tiles of 64 queries)
#define CHQ 16             // queries per embed chunk
#define PLP 20             // LDS pitch for 16-col tiles (16B-aligned rows)

// d_ws: u64 slot[64][256][8] = 1 MB, zeroed per launch
#define WS_CLEAR_BYTES (B_BATCH * NQ * NBLK * 8)

// ---------------------------------------------------------------------------
// ONE launch, two block roles:
//  - gid < 512: FPS block — EXACT R12/R18/R19 configuration (the empirical
//    optimum ~501us; R13-R17 proved every sync-chain variant regresses:
//    cross-block slots live at the L3/IF coherence point). FROZEN.
//  - gid >= 512: EMBED block — overlaps the MLP with FPS. For its 16-query
//    chunk it polls ONLY the chunk's LAST slot line (8 lanes, relaxed,
//    s_sleep backoff; <=1 poller per line -> no storm, R13/R15 lesson).
//    Per-fps-block program order (one line per round, ~2us apart) implies
//    older lines are visible once the last is. It then reads the 128 packs,
//    reconstructs winners (query 0 = point 0 synthesized), gathers coords,
//    and runs the proven R19 MLP micro-structure (acc[4][4], W from L2).
//    MLP/chunk ~14us < chunk production 32us -> trails by one chunk; tail
//    after FPS end ~15us. R20's failure (phases inside FPS waves serialized
//    the rounds) is avoided: separate blocks, FPS path untouched.
// ---------------------------------------------------------------------------
__global__ __attribute__((amdgpu_flat_work_group_size(FPS_T, FPS_T),
                          amdgpu_waves_per_eu(2, 2)))
void fps_embed_kernel(const float* __restrict__ xyz,
                      const float* __restrict__ pcmin,
                      const float* __restrict__ pcmax,
                      const float* __restrict__ G,
                      const float* __restrict__ W1, const float* __restrict__ b1,
                      const float* __restrict__ W2, const float* __restrict__ b2,
                      float* __restrict__ qout, float* __restrict__ eout,
                      unsigned long long* __restrict__ gslot) {
  const int gid = blockIdx.x;
  const int t = threadIdx.x;

  __shared__ unsigned long long sred[FPS_T / 64];
  __shared__ float4 bc;
  __shared__ __align__(16) float Pl[DD][PLP];   // 20480 B
  __shared__ __align__(16) float Hl[DD][PLP];   // 20480 B
  __shared__ int swidx[CHQ];
  __shared__ float snrm[CHQ][3];

  if (gid < FPS_BLOCKS) {
    // ======================= FPS path (FROZEN R12) ========================
    const int xcd = gid & 7;
    const int s = gid >> 3;
    const int b = xcd + 8 * (s >> 3);
    const int q = s & 7;

    const float* __restrict__ base = xyz + (size_t)b * (FPS_N * 3);
    const float4* __restrict__ base4 =
        (const float4*)(base + (size_t)q * PPB * 3) + (size_t)t * (PPT * 3 / 4);
    float* qb = qout + (size_t)b * (NQ * 3);
    unsigned long long* bslot = gslot + (size_t)b * (NQ * NBLK);

    float4 C[PPT * 3 / 4];
#pragma unroll
    for (int i = 0; i < PPT * 3 / 4; ++i) C[i] = base4[i];
#pragma unroll
    for (int i = 0; i < PPT * 3 / 4; ++i) {   // pin: forbid remat
      asm volatile("" : "+v"(C[i].x), "+v"(C[i].y), "+v"(C[i].z), "+v"(C[i].w));
    }
    float4 Dst[NCH];
#pragma unroll
    for (int c = 0; c < NCH; ++c) Dst[c] = make_float4(1e10f, 1e10f, 1e10f, 1e10f);

    if (q == 0 && t == 0) { qb[0] = base[0]; qb[1] = base[1]; qb[2] = base[2]; }
    float cx = base[0], cy = base[1], cz = base[2];   // inds[0] == 0

#pragma unroll 1
    for (int j = 1; j < NQ; ++j) {
      float best = -1.0f;
      int bik = 0;

#pragma unroll
      for (int c = 0; c < NCH; ++c) {
        const float4 a4 = C[3 * c + 0];
        const float4 b4 = C[3 * c + 1];
        const float4 c4 = C[3 * c + 2];
        const float px[4] = {a4.x, a4.w, b4.z, c4.y};
        const float py[4] = {a4.y, b4.x, b4.w, c4.z};
        const float pz[4] = {a4.z, b4.y, c4.x, c4.w};
        const float dold[4] = {Dst[c].x, Dst[c].y, Dst[c].z, Dst[c].w};
        float dnew[4];
#pragma unroll
        for (int i = 0; i < 4; ++i) {
          const float dx = __fsub_rn(px[i], cx);
          const float dy = __fsub_rn(py[i], cy);
          const float dz = __fsub_rn(pz[i], cz);
          const float d = __fadd_rn(__fadd_rn(__fmul_rn(dx, dx), __fmul_rn(dy, dy)),
                                    __fmul_rn(dz, dz));
          const float nd = fminf(dold[i], d);
          dnew[i] = nd;
          if (nd > best) { best = nd; bik = c * 4 + i; }
        }
        Dst[c] = make_float4(dnew[0], dnew[1], dnew[2], dnew[3]);
      }
      int bi = q * PPB + t * PPT + bik;

#pragma unroll
      for (int off = 32; off; off >>= 1) {
        const float ov = __shfl_xor(best, off);
        const int oi = __shfl_xor(bi, off);
        if (ov > best || (ov == best && oi < bi)) { best = ov; bi = oi; }
      }
      if ((t & 63) == 0) {
        sred[t >> 6] = ((unsigned long long)(unsigned int)__float_as_int(best) << 32) |
                       (unsigned int)~(unsigned int)bi;
      }
      __syncthreads();

      if (t < 64) {
        unsigned long long p = sred[t & 3];
#pragma unroll
        for (int off = 1; off < 4; off <<= 1) {
          const unsigned long long o = __shfl_xor(p, off);
          if (o > p) p = o;
        }
        if (t == 0) {
          __hip_atomic_store(&bslot[j * NBLK + q], p, __ATOMIC_RELAXED,
                             __HIP_MEMORY_SCOPE_AGENT);
        }
        unsigned long long rp = 0;
        if (t < NBLK) {
          const unsigned long long* sl = &bslot[j * NBLK + t];
          do {
            rp = __hip_atomic_load(sl, __ATOMIC_RELAXED, __HIP_MEMORY_SCOPE_AGENT);
          } while (rp == 0ull);
        }
#pragma unroll
        for (int off = 1; off < NBLK; off <<= 1) {
          const unsigned long long o = __shfl_xor(rp, off);
          if (o > rp) rp = o;
        }
        if (t == 0) {
          const int gi = (int)~(unsigned int)(rp & 0xffffffffull);
          const float* cp = base + 3 * (size_t)gi;
          const float ncx = cp[0], ncy = cp[1], ncz = cp[2];
          bc = make_float4(ncx, ncy, ncz, 0.f);
          if (q == 0) { qb[3 * j + 0] = ncx; qb[3 * j + 1] = ncy; qb[3 * j + 2] = ncz; }
        }
      }
      __syncthreads();
      cx = bc.x; cy = bc.y; cz = bc.z;
    }
  } else {
    // ======================= EMBED path ========================
    const int eid = gid - FPS_BLOCKS;
    const int b = eid >> 2;
    const int n0 = (eid & 3) * 64;
    const float* __restrict__ base = xyz + (size_t)b * (FPS_N * 3);
    unsigned long long* bslot = gslot + (size_t)b * (NQ * NBLK);
    float* ob = eout + (size_t)b * (DD * NQ);

    const float mn0 = pcmin[3 * b + 0], mn1 = pcmin[3 * b + 1], mn2 = pcmin[3 * b + 2];
    const float mx0 = pcmax[3 * b + 0], mx1 = pcmax[3 * b + 1], mx2 = pcmax[3 * b + 2];
    const int ty = t >> 2, tx = t & 3;   // ty: 4 d-rows, tx: 4 query cols

#pragma unroll 1
    for (int ch = 0; ch < 64 / CHQ; ++ch) {
      const int j0 = n0 + ch * CHQ;
      // poll ONLY the chunk's last line (8 lanes, relaxed, backoff)
      if (t < NBLK) {
        const unsigned long long* sl = &bslot[(size_t)(j0 + CHQ - 1) * NBLK + t];
        while (__hip_atomic_load(sl, __ATOMIC_RELAXED,
                                 __HIP_MEMORY_SCOPE_AGENT) == 0ull) {
          __builtin_amdgcn_s_sleep(2);
        }
      }
      __syncthreads();
      // winners for 16 lines: tid<128 -> (line, slot)
      unsigned long long p = 0xffffffffull;   // line-0 synth: idx 0 (~idx=all-ones)
      if (t < 128) {
        const int line = j0 + (t >> 3);
        if (line > 0) {
          p = __hip_atomic_load(&bslot[(size_t)line * NBLK + (t & 7)],
                                __ATOMIC_RELAXED, __HIP_MEMORY_SCOPE_AGENT);
        }
      }
#pragma unroll
      for (int off = 1; off < 8; off <<= 1) {
        const unsigned long long o = __shfl_xor(p, off);
        if (o > p) p = o;
      }
      if (t < 128 && (t & 7) == 0) {
        swidx[t >> 3] = (int)~(unsigned int)(p & 0xffffffffull);
      }
      __syncthreads();
      if (t < CHQ) {
        const int gi = swidx[t];
        snrm[t][0] = (base[3 * gi + 0] - mn0) / (mx0 - mn0);
        snrm[t][1] = (base[3 * gi + 1] - mn1) / (mx1 - mn1);
        snrm[t][2] = (base[3 * gi + 2] - mn2) / (mx2 - mn2);
      }
      __syncthreads();
      {  // pos embed: qi = t&15, freq block = t>>4
        const int qi = t & 15;
        const int fb = t >> 4;
        const float nx = snrm[qi][0], ny = snrm[qi][1], nz = snrm[qi][2];
#pragma unroll
        for (int it = 0; it < 8; ++it) {
          const int f = fb + it * 16;
          const float sfv = nx * G[f] + ny * G[128 + f] + nz * G[256 + f];
          const float pr = 6.28318530717958647692f * sfv;
          Pl[f][qi] = sinf(pr);
          Pl[f + 128][qi] = cosf(pr);
        }
      }
      __syncthreads();
      {  // layer1: rows ty*4+i, cols tx*4+k (R19 micro-structure)
        float acc[4][4] = {};
        const float* wr0 = W1 + (size_t)(ty * 4 + 0) * DD;
        const float* wr1 = wr0 + DD;
        const float* wr2 = wr1 + DD;
        const float* wr3 = wr2 + DD;
#pragma unroll 2
        for (int c = 0; c < DD; c += 4) {
          const float4 a0 = *(const float4*)(wr0 + c);
          const float4 a1 = *(const float4*)(wr1 + c);
          const float4 a2 = *(const float4*)(wr2 + c);
          const float4 a3 = *(const float4*)(wr3 + c);
          const float4 p0 = *(const float4*)&Pl[c + 0][tx * 4];
          const float4 p1 = *(const float4*)&Pl[c + 1][tx * 4];
          const float4 p2 = *(const float4*)&Pl[c + 2][tx * 4];
          const float4 p3 = *(const float4*)&Pl[c + 3][tx * 4];
          const float av[4][4] = {{a0.x, a0.y, a0.z, a0.w},
                                  {a1.x, a1.y, a1.z, a1.w},
                                  {a2.x, a2.y, a2.z, a2.w},
                                  {a3.x, a3.y, a3.z, a3.w}};
          const float pv[4][4] = {{p0.x, p0.y, p0.z, p0.w},
                                  {p1.x, p1.y, p1.z, p1.w},
                                  {p2.x, p2.y, p2.z, p2.w},
                                  {p3.x, p3.y, p3.z, p3.w}};
#pragma unroll
          for (int cj = 0; cj < 4; ++cj)
#pragma unroll
            for (int i = 0; i < 4; ++i)
#pragma unroll
              for (int k = 0; k < 4; ++k)
                acc[i][k] = fmaf(av[i][cj], pv[cj][k], acc[i][k]);
        }
#pragma unroll
        for (int i = 0; i < 4; ++i) {
          const float bv = b1[ty * 4 + i];
          float4 h;
          h.x = fmaxf(acc[i][0] + bv, 0.f);
          h.y = fmaxf(acc[i][1] + bv, 0.f);
          h.z = fmaxf(acc[i][2] + bv, 0.f);
          h.w = fmaxf(acc[i][3] + bv, 0.f);
          *(float4*)&Hl[ty * 4 + i][tx * 4] = h;
        }
      }
      __syncthreads();
      {  // layer2 -> out
        float acc[4][4] = {};
        const float* wr0 = W2 + (size_t)(ty * 4 + 0) * DD;
        const float* wr1 = wr0 + DD;
        const float* wr2 = wr1 + DD;
        const float* wr3 = wr2 + DD;
#pragma unroll 2
        for (int c = 0; c < DD; c += 4) {
          const float4 a0 = *(const float4*)(wr0 + c);
          const float4 a1 = *(const float4*)(wr1 + c);
          const float4 a2 = *(const float4*)(wr2 + c);
          const float4 a3 = *(const float4*)(wr3 + c);
          const float4 p0 = *(const float4*)&Hl[c + 0][tx * 4];
          const float4 p1 = *(const float4*)&Hl[c + 1][tx * 4];
          const float4 p2 = *(const float4*)&Hl[c + 2][tx * 4];
          const float4 p3 = *(const float4*)&Hl[c + 3][tx * 4];
          const float av[4][4] = {{a0.x, a0.y, a0.z, a0.w},
                                  {a1.x, a1.y, a1.z, a1.w},
                                  {a2.x, a2.y, a2.z, a2.w},
                                  {a3.x, a3.y, a3.z, a3.w}};
          const float pv[4][4] = {{p0.x, p0.y, p0.z, p0.w},
                                  {p1.x, p1.y, p1.z, p1.w},
                                  {p2.x, p2.y, p2.z, p2.w},
                                  {p3.x, p3.y, p3.z, p3.w}};
#pragma unroll
          for (int cj = 0; cj < 4; ++cj)
#pragma unroll
            for (int i = 0; i < 4; ++i)
#pragma unroll
              for (int k = 0; k < 4; ++k)
                acc[i][k] = fmaf(av[i][cj], pv[cj][k], acc[i][k]);
        }
#pragma unroll
        for (int i = 0; i < 4; ++i) {
          const float bv = b2[ty * 4 + i];
          float4 h;
          h.x = fmaxf(acc[i][0] + bv, 0.f);
          h.y = fmaxf(acc[i][1] + bv, 0.f);
          h.z = fmaxf(acc[i][2] + bv, 0.f);
          h.w = fmaxf(acc[i][3] + bv, 0.f);
          *(float4*)(ob + (size_t)(ty * 4 + i) * NQ + j0 + tx * 4) = h;
        }
      }
      __syncthreads();
    }
  }
}

extern "C" void kernel_launch(void* const* d_in, const int* in_sizes, int n_in,
                              void* d_out, int out_size, void* d_ws, size_t ws_size,
                              hipStream_t stream) {
  (void)in_sizes; (void)n_in; (void)ws_size; (void)out_size;
  const float* xyz   = (const float*)d_in[0];
  const float* pcmin = (const float*)d_in[1];
  const float* pcmax = (const float*)d_in[2];
  const float* G     = (const float*)d_in[3];
  const float* W1    = (const float*)d_in[4];
  const float* b1    = (const float*)d_in[5];
  const float* W2    = (const float*)d_in[6];
  const float* b2    = (const float*)d_in[7];

  float* qxyz  = (float*)d_out;                       // [64][256][3]
  float* embed = qxyz + (size_t)B_BATCH * NQ * 3;     // [64][256][256]

  unsigned long long* gslot = (unsigned long long*)d_ws;

  // clear sync slots every launch (deterministic across graph replays)
  hipMemsetAsync(d_ws, 0, WS_CLEAR_BYTES, stream);

  hipLaunchKernelGGL(fps_embed_kernel, dim3(FPS_BLOCKS + EMB_BLOCKS),
                     dim3(FPS_T), 0, stream, xyz, pcmin, pcmax, G,
                     W1, b1, W2, b2, qxyz, embed, gslot);
}

// Round 22
// 576.560 us; speedup vs baseline: 4.7759x; 1.0796x over previous
//
#include <hip/hip_runtime.h>

#define FPS_N 32768
#define FPS_T 256          // threads per block
#define NBLK 8             // fps blocks per batch
#define PPB (FPS_N / NBLK) // 4096 points per block
#define PPT (PPB / FPS_T)  // 16 points per thread
#define NCH (PPT / 4)      // 4 four-point chunks per thread
#define NQ 256
#define DD 256
#define B_BATCH 64
#define CHQ 16             // queries per embed block
#define PLP 20             // LDS pitch for 16-col tiles (16B-aligned rows)

// d_ws: u64 slot[64][256][8] = 1 MB, zeroed per launch
#define WS_CLEAR_BYTES (B_BATCH * NQ * NBLK * 8)

// ---------------------------------------------------------------------------
// Kernel 1: furthest point sampling — EXACT R12/R18/R19 configuration (the
// empirical optimum ~501us). R13-R17 and R20/R21 (in-wave and co-resident
// MLP overlap) all regressed: the 255 serial rounds live at the L3/IF
// coherence RT floor and need every CU slot. FROZEN — do not modify.
// ---------------------------------------------------------------------------
__global__ __attribute__((amdgpu_flat_work_group_size(FPS_T, FPS_T),
                          amdgpu_waves_per_eu(2, 2)))
void fps_kernel(const float* __restrict__ xyz, float* __restrict__ qout,
                unsigned long long* __restrict__ gslot) {
  const int gid = blockIdx.x;
  const int xcd = gid & 7;          // round-robin dispatch: block i -> XCD i%8
  const int s = gid >> 3;
  const int b = xcd + 8 * (s >> 3); // all 8 eighths of batch b on same XCD
  const int q = s & 7;
  const int t = threadIdx.x;

  const float* __restrict__ base = xyz + (size_t)b * (FPS_N * 3);
  const float4* __restrict__ base4 =
      (const float4*)(base + (size_t)q * PPB * 3) + (size_t)t * (PPT * 3 / 4);
  float* qb = qout + (size_t)b * (NQ * 3);
  unsigned long long* bslot = gslot + (size_t)b * (NQ * NBLK);

  __shared__ unsigned long long sred[FPS_T / 64];
  __shared__ float4 bc;   // broadcast: cx, cy, cz

  // persistent registers: coords 12 float4 = 48 VGPR, dist 4 float4 = 16 VGPR
  float4 C[PPT * 3 / 4];
#pragma unroll
  for (int i = 0; i < PPT * 3 / 4; ++i) C[i] = base4[i];
#pragma unroll
  for (int i = 0; i < PPT * 3 / 4; ++i) {   // pin: forbid remat
    asm volatile("" : "+v"(C[i].x), "+v"(C[i].y), "+v"(C[i].z), "+v"(C[i].w));
  }
  float4 Dst[NCH];
#pragma unroll
  for (int c = 0; c < NCH; ++c) Dst[c] = make_float4(1e10f, 1e10f, 1e10f, 1e10f);

  if (q == 0 && t == 0) { qb[0] = base[0]; qb[1] = base[1]; qb[2] = base[2]; }
  float cx = base[0], cy = base[1], cz = base[2];   // inds[0] == 0

#pragma unroll 1
  for (int j = 1; j < NQ; ++j) {
    float best = -1.0f;
    int bik = 0;

#pragma unroll
    for (int c = 0; c < NCH; ++c) {
      const float4 a4 = C[3 * c + 0];
      const float4 b4 = C[3 * c + 1];
      const float4 c4 = C[3 * c + 2];
      // unpack 12 floats -> 4 points (register renaming, no real ops)
      const float px[4] = {a4.x, a4.w, b4.z, c4.y};
      const float py[4] = {a4.y, b4.x, b4.w, c4.z};
      const float pz[4] = {a4.z, b4.y, c4.x, c4.w};
      const float dold[4] = {Dst[c].x, Dst[c].y, Dst[c].z, Dst[c].w};
      float dnew[4];
#pragma unroll
      for (int i = 0; i < 4; ++i) {
        const float dx = __fsub_rn(px[i], cx);
        const float dy = __fsub_rn(py[i], cy);
        const float dz = __fsub_rn(pz[i], cz);
        // numpy order: (dx^2 + dy^2) + dz^2, no fma
        const float d = __fadd_rn(__fadd_rn(__fmul_rn(dx, dx), __fmul_rn(dy, dy)),
                                  __fmul_rn(dz, dz));
        const float nd = fminf(dold[i], d);
        dnew[i] = nd;
        if (nd > best) { best = nd; bik = c * 4 + i; }  // strict >: first occ.
      }
      Dst[c] = make_float4(dnew[0], dnew[1], dnew[2], dnew[3]);
    }
    int bi = q * PPB + t * PPT + bik;   // global point index

    // wave (64-lane) argmax reduce with first-index tie-break
#pragma unroll
    for (int off = 32; off; off >>= 1) {
      const float ov = __shfl_xor(best, off);
      const int oi = __shfl_xor(bi, off);
      if (ov > best || (ov == best && oi < bi)) { best = ov; bi = oi; }
    }
    // pack: monotone in dist (f32>=0), ~idx -> max picks smallest index
    if ((t & 63) == 0) {
      sred[t >> 6] = ((unsigned long long)(unsigned int)__float_as_int(best) << 32) |
                     (unsigned int)~(unsigned int)bi;
    }
    __syncthreads();

    if (t < 64) {   // wave 0 handles block combine + cross-block sync
      unsigned long long p = sred[t & 3];
#pragma unroll
      for (int off = 1; off < 4; off <<= 1) {
        const unsigned long long o = __shfl_xor(p, off);
        if (o > p) p = o;
      }
      // p = this block's pack (identical in lanes 0-7)
      if (t == 0) {
        __hip_atomic_store(&bslot[j * NBLK + q], p, __ATOMIC_RELAXED,
                           __HIP_MEMORY_SCOPE_AGENT);
      }
      unsigned long long rp = 0;
      if (t < NBLK) {
        const unsigned long long* sl = &bslot[j * NBLK + t];
        do {
          rp = __hip_atomic_load(sl, __ATOMIC_RELAXED, __HIP_MEMORY_SCOPE_AGENT);
        } while (rp == 0ull);
      }
#pragma unroll
      for (int off = 1; off < NBLK; off <<= 1) {
        const unsigned long long o = __shfl_xor(rp, off);
        if (o > rp) rp = o;
      }
      if (t == 0) {
        const int gi = (int)~(unsigned int)(rp & 0xffffffffull);
        const float* cp = base + 3 * (size_t)gi;
        const float ncx = cp[0], ncy = cp[1], ncz = cp[2];
        bc = make_float4(ncx, ncy, ncz, 0.f);
        if (q == 0) { qb[3 * j + 0] = ncx; qb[3 * j + 1] = ncy; qb[3 * j + 2] = ncz; }
      }
    }
    __syncthreads();
    cx = bc.x; cy = bc.y; cz = bc.z;
  }
}

// ---------------------------------------------------------------------------
// Kernel 2: fourier positional embedding + 2-layer MLP.
// R22 change: 16-query tiles (was 64) -> LDS 41KB -> 3 blocks/CU
// (3 waves/SIMD) instead of 1 wave/SIMD; 1024 blocks. The R19 structure was
// occupancy-starved (140KB LDS = 1 block/CU), exposing every W-load stall:
// ~50us vs the 27us FMA bound. Same proven micro-structure (acc[4][4],
// W streamed from L2 — barrier-free inner loop, 5 barriers total).
// ---------------------------------------------------------------------------
__global__ __launch_bounds__(256) void embed_mlp_kernel(
    const float* __restrict__ qxyz, const float* __restrict__ pcmin,
    const float* __restrict__ pcmax, const float* __restrict__ G,
    const float* __restrict__ W1, const float* __restrict__ b1,
    const float* __restrict__ W2, const float* __restrict__ b2,
    float* __restrict__ out) {
  const int eid = blockIdx.x;
  const int b = eid >> 4;
  const int j0 = (eid & 15) * CHQ;
  const int t = threadIdx.x;
  const int ty = t >> 2, tx = t & 3;   // ty: 64 row-quads, tx: 4 query cols

  __shared__ __align__(16) float Pl[DD][PLP];   // 20480 B
  __shared__ __align__(16) float Hl[DD][PLP];   // 20480 B
  __shared__ float snrm[CHQ][3];

  const float* qb = qxyz + (size_t)b * (NQ * 3);
  float* ob = out + (size_t)b * (DD * NQ);

  if (t < CHQ) {
    const int n = j0 + t;
    snrm[t][0] = (qb[3 * n + 0] - pcmin[3 * b + 0]) / (pcmax[3 * b + 0] - pcmin[3 * b + 0]);
    snrm[t][1] = (qb[3 * n + 1] - pcmin[3 * b + 1]) / (pcmax[3 * b + 1] - pcmin[3 * b + 1]);
    snrm[t][2] = (qb[3 * n + 2] - pcmin[3 * b + 2]) / (pcmax[3 * b + 2] - pcmin[3 * b + 2]);
  }
  __syncthreads();

  {  // pos embed: qi = t&15, freq base fb = t>>4 (0..15), 8 freqs each
    const int qi = t & 15;
    const int fb = t >> 4;
    const float nx = snrm[qi][0], ny = snrm[qi][1], nz = snrm[qi][2];
#pragma unroll
    for (int it = 0; it < 8; ++it) {
      const int f = fb + it * 16;
      const float sfv = nx * G[f] + ny * G[128 + f] + nz * G[256 + f];
      const float pr = 6.28318530717958647692f * sfv;
      Pl[f][qi] = sinf(pr);
      Pl[f + 128][qi] = cosf(pr);
    }
  }
  __syncthreads();

  {  // layer1: rows ty*4+i, cols tx*4+k
    float acc[4][4] = {};
    const float* wr0 = W1 + (size_t)(ty * 4 + 0) * DD;
    const float* wr1 = wr0 + DD;
    const float* wr2 = wr1 + DD;
    const float* wr3 = wr2 + DD;
#pragma unroll 2
    for (int c = 0; c < DD; c += 4) {
      const float4 a0 = *(const float4*)(wr0 + c);
      const float4 a1 = *(const float4*)(wr1 + c);
      const float4 a2 = *(const float4*)(wr2 + c);
      const float4 a3 = *(const float4*)(wr3 + c);
      const float4 p0 = *(const float4*)&Pl[c + 0][tx * 4];
      const float4 p1 = *(const float4*)&Pl[c + 1][tx * 4];
      const float4 p2 = *(const float4*)&Pl[c + 2][tx * 4];
      const float4 p3 = *(const float4*)&Pl[c + 3][tx * 4];
      const float av[4][4] = {{a0.x, a0.y, a0.z, a0.w},
                              {a1.x, a1.y, a1.z, a1.w},
                              {a2.x, a2.y, a2.z, a2.w},
                              {a3.x, a3.y, a3.z, a3.w}};
      const float pv[4][4] = {{p0.x, p0.y, p0.z, p0.w},
                              {p1.x, p1.y, p1.z, p1.w},
                              {p2.x, p2.y, p2.z, p2.w},
                              {p3.x, p3.y, p3.z, p3.w}};
#pragma unroll
      for (int cj = 0; cj < 4; ++cj)
#pragma unroll
        for (int i = 0; i < 4; ++i)
#pragma unroll
          for (int k = 0; k < 4; ++k)
            acc[i][k] = fmaf(av[i][cj], pv[cj][k], acc[i][k]);
    }
#pragma unroll
    for (int i = 0; i < 4; ++i) {
      const float bv = b1[ty * 4 + i];
      float4 h;
      h.x = fmaxf(acc[i][0] + bv, 0.f);
      h.y = fmaxf(acc[i][1] + bv, 0.f);
      h.z = fmaxf(acc[i][2] + bv, 0.f);
      h.w = fmaxf(acc[i][3] + bv, 0.f);
      *(float4*)&Hl[ty * 4 + i][tx * 4] = h;
    }
  }
  __syncthreads();

  {  // layer2 -> out
    float acc[4][4] = {};
    const float* wr0 = W2 + (size_t)(ty * 4 + 0) * DD;
    const float* wr1 = wr0 + DD;
    const float* wr2 = wr1 + DD;
    const float* wr3 = wr2 + DD;
#pragma unroll 2
    for (int c = 0; c < DD; c += 4) {
      const float4 a0 = *(const float4*)(wr0 + c);
      const float4 a1 = *(const float4*)(wr1 + c);
      const float4 a2 = *(const float4*)(wr2 + c);
      const float4 a3 = *(const float4*)(wr3 + c);
      const float4 p0 = *(const float4*)&Hl[c + 0][tx * 4];
      const float4 p1 = *(const float4*)&Hl[c + 1][tx * 4];
      const float4 p2 = *(const float4*)&Hl[c + 2][tx * 4];
      const float4 p3 = *(const float4*)&Hl[c + 3][tx * 4];
      const float av[4][4] = {{a0.x, a0.y, a0.z, a0.w},
                              {a1.x, a1.y, a1.z, a1.w},
                              {a2.x, a2.y, a2.z, a2.w},
                              {a3.x, a3.y, a3.z, a3.w}};
      const float pv[4][4] = {{p0.x, p0.y, p0.z, p0.w},
                              {p1.x, p1.y, p1.z, p1.w},
                              {p2.x, p2.y, p2.z, p2.w},
                              {p3.x, p3.y, p3.z, p3.w}};
#pragma unroll
      for (int cj = 0; cj < 4; ++cj)
#pragma unroll
        for (int i = 0; i < 4; ++i)
#pragma unroll
          for (int k = 0; k < 4; ++k)
            acc[i][k] = fmaf(av[i][cj], pv[cj][k], acc[i][k]);
    }
#pragma unroll
    for (int i = 0; i < 4; ++i) {
      const float bv = b2[ty * 4 + i];
      float4 h;
      h.x = fmaxf(acc[i][0] + bv, 0.f);
      h.y = fmaxf(acc[i][1] + bv, 0.f);
      h.z = fmaxf(acc[i][2] + bv, 0.f);
      h.w = fmaxf(acc[i][3] + bv, 0.f);
      *(float4*)(ob + (size_t)(ty * 4 + i) * NQ + j0 + tx * 4) = h;
    }
  }
}

extern "C" void kernel_launch(void* const* d_in, const int* in_sizes, int n_in,
                              void* d_out, int out_size, void* d_ws, size_t ws_size,
                              hipStream_t stream) {
  (void)in_sizes; (void)n_in; (void)ws_size; (void)out_size;
  const float* xyz   = (const float*)d_in[0];
  const float* pcmin = (const float*)d_in[1];
  const float* pcmax = (const float*)d_in[2];
  const float* G     = (const float*)d_in[3];
  const float* W1    = (const float*)d_in[4];
  const float* b1    = (const float*)d_in[5];
  const float* W2    = (const float*)d_in[6];
  const float* b2    = (const float*)d_in[7];

  float* qxyz  = (float*)d_out;                       // [64][256][3]
  float* embed = qxyz + (size_t)B_BATCH * NQ * 3;     // [64][256][256]

  unsigned long long* gslot = (unsigned long long*)d_ws;

  // clear sync slots every launch (deterministic across graph replays)
  hipMemsetAsync(d_ws, 0, WS_CLEAR_BYTES, stream);

  hipLaunchKernelGGL(fps_kernel, dim3(B_BATCH * NBLK), dim3(FPS_T), 0, stream,
                     xyz, qxyz, gslot);
  hipLaunchKernelGGL(embed_mlp_kernel, dim3(B_BATCH * 16), dim3(256), 0, stream,
                     qxyz, pcmin, pcmax, G, W1, b1, W2, b2, embed);
}